// Round 11
// baseline (960.050 us; speedup 1.0000x reference)
//
#include <hip/hip_runtime.h>
#include <math.h>

#define S_  5
#define B_  2
#define C_  128
#define N_  576
#define SB  10
#define NPAIR 40
#define C2  256

typedef short v8s __attribute__((ext_vector_type(8)));
typedef float v4f __attribute__((ext_vector_type(4)));

#define GLOBAL_AS __attribute__((address_space(1)))
#define LDS_AS    __attribute__((address_space(3)))

__device__ __forceinline__ unsigned short f2bf(float f) {
    union { float f; unsigned u; } v; v.f = f;
    unsigned r = (v.u + 0x7FFF + ((v.u >> 16) & 1)) >> 16;
    return (unsigned short)r;
}
__device__ __forceinline__ float bf2f(unsigned short h) {
    union { unsigned u; float f; } v; v.u = ((unsigned)h) << 16;
    return v.f;
}

// ------------------------------------------------------------------ weight packs
// Fragment-major A: [cgb][kk][ch][g][tap_l][c(4)][l15(16)][quad(4)][j(8)]
__global__ void packA5_kernel(const float* __restrict__ w, unsigned short* __restrict__ Apk, int M)
{
    int idx = blockIdx.x * 256 + threadIdx.x;
    if (idx >= M * 6400) return;
    int r = idx;
    int j = r & 7;      r >>= 3;
    int quad = r & 3;   r >>= 2;
    int l15 = r & 15;   r >>= 4;
    int c = r & 3;      r >>= 2;
    int tap_l = r % 5;  r /= 5;
    int g = r % 5;      r /= 5;
    int ch = r & 1;     r >>= 1;
    int kk = r & 3;     r >>= 2;
    int cgb = r;
    int co = cgb * 64 + c * 16 + l15;
    int ci = kk * 64 + ch * 32 + quad * 8 + j;
    int tap = g * 5 + tap_l;
    Apk[idx] = f2bf(w[((size_t)co * 256 + ci) * 25 + tap]);
}
__global__ void packA3_kernel(const float* __restrict__ wf, const float* __restrict__ wh,
                              const float* __restrict__ wl, unsigned short* __restrict__ Apk)
{
    int idx = blockIdx.x * 256 + threadIdx.x;
    if (idx >= 384 * 1152) return;
    int r = idx;
    int j = r & 7;      r >>= 3;
    int quad = r & 3;   r >>= 2;
    int l15 = r & 15;   r >>= 4;
    int c = r & 3;      r >>= 2;
    int tap_l = r % 3;  r /= 3;
    int g = r % 3;      r /= 3;
    int ch = r & 1;     r >>= 1;
    int kk = r & 1;     r >>= 1;
    int cgb = r;
    int co = cgb * 64 + c * 16 + l15;
    const float* w = (co < 128) ? wf : (co < 256) ? wh : wl;
    int cl = co & 127;
    int ci = kk * 64 + ch * 32 + quad * 8 + j;
    int tap = g * 3 + tap_l;
    Apk[idx] = f2bf(w[((size_t)cl * 128 + ci) * 9 + tap]);
}
__global__ void packWc_kernel(const float* __restrict__ w, unsigned short* __restrict__ o)
{
    int idx = blockIdx.x * 256 + threadIdx.x;
    if (idx < 128 * 128) o[idx] = f2bf(w[idx]);
}

// ---------------------------------------------- transpose-cast (x at it=0, rhb)
// zrp != null: multiply by r = sigmoid(sum_{k<4} zrp[k][128+c] + zrb[128+c])
// vfd != null: also emit V-fragment-packed bf16
__global__ __launch_bounds__(256) void tc_kernel(
    const float* __restrict__ src, const float* __restrict__ zrp,
    const float* __restrict__ zrb,
    unsigned short* __restrict__ dst, unsigned short* __restrict__ vfd)
{
    const size_t PLANE = (size_t)SB * C2 * N_;
    __shared__ float tile[128][65];
    int img = blockIdx.y, px0 = blockIdx.x * 64, t = threadIdx.x;
    #pragma unroll
    for (int i = 0; i < 32; ++i) {
        int e = i * 256 + t; int ci = e >> 6; int px = e & 63;
        float v = src[((size_t)img * 128 + ci) * 576 + px0 + px];
        if (zrp) {
            size_t zi = ((size_t)img * C2 + 128 + ci) * 576 + px0 + px;
            float a = zrb[128 + ci];
            #pragma unroll
            for (int k = 0; k < 4; ++k) a += zrp[k * PLANE + zi];
            v *= 1.f / (1.f + __expf(-a));
        }
        tile[ci][px] = v;
        if (vfd) {
            int m = px0 + px;
            int ctile = ci >> 4, l15v = ci & 15;
            int sIdx = m >> 5, quadv = (m >> 3) & 3, j = m & 7;
            vfd[(((size_t)img * 8 + ctile) * 18 + sIdx) * 512 + (quadv * 16 + l15v) * 8 + j] = f2bf(v);
        }
    }
    __syncthreads();
    #pragma unroll
    for (int i = 0; i < 32; ++i) {
        int e = i * 256 + t; int px = e >> 7; int ci = e & 127;
        dst[((size_t)img * 576 + px0 + px) * 128 + ci] = f2bf(tile[ci][px]);
    }
}

// ------------------------------------------------------ MFMA implicit-GEMM conv v7
// MODE 0: f32 partial planes per kk (5x5 convs, SPLITK=4)
// MODE 1: conv3 full-K fused epilogue: +bias, write ftT(Q) / KFa(K-pack) / VFa(V-pack)
template<int KD, int R, int CINT, int SPLITK, int MODE>
__global__ __launch_bounds__(256, 1) void conv_mfma(
    const unsigned short* __restrict__ srcA, const unsigned short* __restrict__ srcB,
    const unsigned short* __restrict__ Apk, int COUT, float* __restrict__ po,
    const float* __restrict__ b0, const float* __restrict__ b1, const float* __restrict__ b2,
    unsigned short* __restrict__ t0, unsigned short* __restrict__ t1,
    unsigned short* __restrict__ t2)
{
    constexpr int PART   = CINT / SPLITK;
    constexpr int NCH    = PART / 32;
    constexpr int NSUB   = NCH * KD;
    constexpr int WR     = 8 + 2 * R;
    constexpr int WC     = 24 + 2 * R;
    constexpr int NPOS   = WR * WC;
    constexpr int NSLOTB = NPOS * 4;
    constexpr int RB     = (NSLOTB + 255) / 256;
    constexpr int AUNITS = KD * 4 * 64;
    constexpr int AR     = AUNITS / 256;
    __shared__ __align__(16) unsigned short Ab[2][AUNITS * 8];
    __shared__ __align__(16) unsigned short Bb[NPOS * 32];

    int f   = blockIdx.x;
    int kk  = f % SPLITK;
    int cgb = f / SPLITK;
    int pxb = blockIdx.y;
    int img = blockIdx.z;
    int t = threadIdx.x;
    int wave = t >> 6, lane = t & 63;
    int quad = lane >> 4, l15 = lane & 15;
    int r0 = pxb * 8;

    const int cibase = kk * PART;
    const unsigned short* src = (cibase >= 128) ? srcB : srcA;
    const int cioff0 = cibase & 127;
    const unsigned short* srcI = src + (size_t)img * 576 * 128;

    int posBase[3], pxs[3];
    #pragma unroll
    for (int s = 0; s < 3; ++s) {
        int px = pxb * 192 + wave * 48 + s * 16 + l15;
        pxs[s] = px;
        int pr = px / 24, pc = px % 24;
        posBase[s] = (pr - r0 + R) * WC + pc + R;
    }

    int goffB[RB]; bool gokB[RB];
    #pragma unroll
    for (int rr = 0; rr < RB; ++rr) {
        int idx = rr * 256 + wave * 64 + lane;
        int pos = idx >> 2, slotq = idx & 3;
        int gr = slotq ^ ((pos >> 1) & 3);
        int wr = pos / WC, wc = pos % WC;
        int grow = r0 - R + wr, gcol = wc - R;
        gokB[rr] = (idx < NSLOTB) && grow >= 0 && grow < 24 && gcol >= 0 && gcol < 24;
        goffB[rr] = (grow * 24 + gcol) * 128 + gr * 8;
    }

    auto stageB = [&](int ch) {
        const unsigned short* sp = srcI + cioff0 + ch * 32;
        #pragma unroll
        for (int rr = 0; rr < RB; ++rr) {
            if (gokB[rr]) {
                __builtin_amdgcn_global_load_lds(
                    (const GLOBAL_AS void*)(sp + goffB[rr]),
                    (LDS_AS void*)((char*)&Bb[0] + (size_t)(rr * 256 + wave * 64) * 16),
                    16, 0, 0);
            }
        }
    };
    auto stageA = [&](int sub, int buf) {
        const unsigned short* sp = Apk + ((size_t)((cgb * SPLITK + kk) * NSUB + sub)) * (AUNITS * 8);
        #pragma unroll
        for (int r = 0; r < AR; ++r) {
            int u0 = r * 256 + wave * 64;
            __builtin_amdgcn_global_load_lds(
                (const GLOBAL_AS void*)(sp + (size_t)(u0 + lane) * 8),
                (LDS_AS void*)((char*)&Ab[buf][0] + (size_t)u0 * 16),
                16, 0, 0);
        }
    };

    v4f acc[4][3];
    #pragma unroll
    for (int c = 0; c < 4; ++c)
        #pragma unroll
        for (int s = 0; s < 3; ++s)
            #pragma unroll
            for (int r = 0; r < 4; ++r) acc[c][s][r] = 0.f;

    {
        v8s zv;
        #pragma unroll
        for (int j = 0; j < 8; ++j) zv[j] = 0;
        for (int i = t; i < NPOS * 4; i += 256) ((v8s*)Bb)[i] = zv;
    }
    __syncthreads();
    stageB(0);
    stageA(0, 0);
    __syncthreads();

    int sub = 0;
    #pragma unroll 1
    for (int ch = 0; ch < NCH; ++ch) {
        #pragma unroll 1
        for (int g = 0; g < KD; ++g) {
            if (sub + 1 < NSUB) stageA(sub + 1, (sub + 1) & 1);
            const unsigned short* Ap = &Ab[sub & 1][0];
            #pragma unroll
            for (int tl = 0; tl < KD; ++tl) {
                int doff = (g - R) * WC + (tl - R);
                v8s a[4];
                #pragma unroll
                for (int c = 0; c < 4; ++c)
                    a[c] = *(const v8s*)&Ap[((tl * 4 + c) * 64 + l15 * 4 + quad) * 8];
                v8s b[3];
                #pragma unroll
                for (int s = 0; s < 3; ++s) {
                    int pos = posBase[s] + doff;
                    b[s] = *(const v8s*)&Bb[pos * 32 + ((quad ^ ((pos >> 1) & 3)) << 3)];
                }
                #pragma unroll
                for (int c = 0; c < 4; ++c)
                    #pragma unroll
                    for (int s = 0; s < 3; ++s)
                        acc[c][s] = __builtin_amdgcn_mfma_f32_16x16x32_bf16(a[c], b[s], acc[c][s], 0, 0, 0);
            }
            __syncthreads();
            ++sub;
        }
        if (ch + 1 < NCH) { stageB(ch + 1); __syncthreads(); }
    }

    if (MODE == 0) {
        float* out = po + (size_t)kk * ((size_t)SB * COUT * 576)
                   + ((size_t)img * COUT + cgb * 64) * 576;
        #pragma unroll
        for (int c = 0; c < 4; ++c)
            #pragma unroll
            for (int s = 0; s < 3; ++s)
                #pragma unroll
                for (int r = 0; r < 4; ++r) {
                    int col = c * 16 + quad * 4 + r;
                    out[(size_t)col * 576 + pxs[s]] = acc[c][s][r];
                }
    } else {
        // conv3 fused: co in [cgb*64, cgb*64+64); which = co>>7
        #pragma unroll
        for (int c = 0; c < 4; ++c)
            #pragma unroll
            for (int s = 0; s < 3; ++s) {
                int px = pxs[s];
                #pragma unroll
                for (int r = 0; r < 4; ++r) {
                    int co = cgb * 64 + c * 16 + quad * 4 + r;
                    int which = co >> 7, cl = co & 127;
                    const float* bp = (which == 0) ? b0 : (which == 1) ? b1 : b2;
                    float v = acc[c][s][r] + bp[cl];
                    if (which == 0) {
                        t0[((size_t)img * 576 + px) * 128 + cl] = f2bf(v);
                    } else if (which == 1) {
                        int mt = px >> 4, l15m = px & 15;
                        int kb = cl >> 5, quadk = (cl >> 3) & 3, jj = cl & 7;
                        t1[(((size_t)img * 36 + mt) * 4 + kb) * 512 + (quadk * 16 + l15m) * 8 + jj] = f2bf(v);
                    } else {
                        int ctile = cl >> 4, l15v = cl & 15;
                        int sIdx = px >> 5, quadv = (px >> 3) & 3, jj = px & 7;
                        t2[(((size_t)img * 8 + ctile) * 18 + sIdx) * 512 + (quadv * 16 + l15v) * 8 + jj] = f2bf(v);
                    }
                }
            }
    }
}

// ---------------------------------------------------------------- yt (MFMA) -> K-packed
__global__ __launch_bounds__(256) void yt_mfma(
    const unsigned short* __restrict__ hT, const unsigned short* __restrict__ Wcb,
    unsigned short* __restrict__ KFi)
{
    int t = threadIdx.x, wave = t >> 6, lane = t & 63;
    int q = lane >> 4, l15 = lane & 15;
    int n0 = blockIdx.x * 16, img = blockIdx.y;
    v4f acc[2];
    #pragma unroll
    for (int ct = 0; ct < 2; ++ct)
        #pragma unroll
        for (int r = 0; r < 4; ++r) acc[ct][r] = 0.f;
    #pragma unroll
    for (int kk = 0; kk < 4; ++kk) {
        v8s b = *(const v8s*)(hT + ((size_t)img * 576 + n0 + l15) * 128 + kk * 32 + q * 8);
        #pragma unroll
        for (int ct = 0; ct < 2; ++ct) {
            v8s a = *(const v8s*)(Wcb + (size_t)((wave * 2 + ct) * 16 + l15) * 128 + kk * 32 + q * 8);
            acc[ct] = __builtin_amdgcn_mfma_f32_16x16x32_bf16(a, b, acc[ct], 0, 0, 0);
        }
    }
    int mt = blockIdx.x;
    #pragma unroll
    for (int ct = 0; ct < 2; ++ct) {
        #pragma unroll
        for (int r = 0; r < 4; ++r) {
            int co = (wave * 2 + ct) * 16 + q * 4 + r;
            int kk = co >> 5, quadk = (co >> 3) & 3, j = co & 7;
            KFi[(((size_t)img * 36 + mt) * 4 + kk) * 512 + (quadk * 16 + l15) * 8 + j]
                = f2bf(acc[ct][r]);
        }
    }
}

// ---------------------------------------------------- MFMA flash attention
template<int MODE>
__global__ __launch_bounds__(256) void attn_mfma(
    const unsigned short* __restrict__ QT, const unsigned short* __restrict__ KF,
    const unsigned short* __restrict__ VF, float* __restrict__ Of,
    unsigned short* __restrict__ Oh, const float* __restrict__ addsrc,
    const float* __restrict__ alpha)
{
    __shared__ __align__(16) unsigned short P[16 * 576];
    __shared__ float redmx[4][16];
    __shared__ float redsm[4][16];
    int t = threadIdx.x;
    int wave = t >> 6, lane = t & 63;
    int q = lane >> 4, l15 = lane & 15;
    int n0 = blockIdx.x * 16;
    int p = blockIdx.y;
    int qimg, kimg;
    if (MODE == 0) { qimg = p; kimg = p; }
    else {
        int b = p & 1; int ij = p >> 1; int i = ij >> 2; int jj = ij & 3;
        int j = jj + (jj >= i ? 1 : 0);
        qimg = i * 2 + b; kimg = j * 2 + b;
    }
    const unsigned short* Qp = QT + ((size_t)qimg * 576 + n0) * 128;
    const unsigned short* Kp = KF + (size_t)kimg * 36 * 4 * 512;
    const unsigned short* Vp = VF + (size_t)kimg * 8 * 18 * 512;

    v8s aq[4];
    #pragma unroll
    for (int kk = 0; kk < 4; ++kk)
        aq[kk] = *(const v8s*)(Qp + (size_t)l15 * 128 + kk * 32 + q * 8);

    v4f S[9];
    #pragma unroll
    for (int i = 0; i < 9; ++i)
        #pragma unroll
        for (int r = 0; r < 4; ++r) S[i][r] = 0.f;

    #pragma unroll
    for (int i = 0; i < 9; ++i) {
        int mt = wave * 9 + i;
        #pragma unroll
        for (int kk = 0; kk < 4; ++kk) {
            v8s b = *(const v8s*)(Kp + ((size_t)(mt * 4 + kk)) * 512 + lane * 8);
            S[i] = __builtin_amdgcn_mfma_f32_16x16x32_bf16(aq[kk], b, S[i], 0, 0, 0);
        }
    }

    float mx[4];
    #pragma unroll
    for (int r = 0; r < 4; ++r) {
        float m = S[0][r];
        #pragma unroll
        for (int i = 1; i < 9; ++i) m = fmaxf(m, S[i][r]);
        #pragma unroll
        for (int off = 1; off < 16; off <<= 1) m = fmaxf(m, __shfl_xor(m, off));
        mx[r] = m;
    }
    if (l15 == 0) {
        #pragma unroll
        for (int r = 0; r < 4; ++r) redmx[wave][q * 4 + r] = mx[r];
    }
    __syncthreads();
    float sum[4];
    #pragma unroll
    for (int r = 0; r < 4; ++r) {
        float g = fmaxf(fmaxf(redmx[0][q * 4 + r], redmx[1][q * 4 + r]),
                        fmaxf(redmx[2][q * 4 + r], redmx[3][q * 4 + r]));
        float s = 0.f;
        #pragma unroll
        for (int i = 0; i < 9; ++i) { float e = __expf(S[i][r] - g); S[i][r] = e; s += e; }
        #pragma unroll
        for (int off = 1; off < 16; off <<= 1) s += __shfl_xor(s, off);
        sum[r] = s;
    }
    if (l15 == 0) {
        #pragma unroll
        for (int r = 0; r < 4; ++r) redsm[wave][q * 4 + r] = sum[r];
    }
    #pragma unroll
    for (int i = 0; i < 9; ++i) {
        int m = (wave * 9 + i) * 16 + l15;
        int cm = m >> 3, mo = m & 7;
        #pragma unroll
        for (int r = 0; r < 4; ++r) {
            int n = q * 4 + r;
            P[n * 576 + ((cm ^ (n & 7)) << 3) + mo] = f2bf(S[i][r]);
        }
    }
    __syncthreads();
    float inv[4];
    #pragma unroll
    for (int r = 0; r < 4; ++r)
        inv[r] = 1.f / (redsm[0][q * 4 + r] + redsm[1][q * 4 + r] +
                        redsm[2][q * 4 + r] + redsm[3][q * 4 + r]);

    v4f o[2];
    #pragma unroll
    for (int ct = 0; ct < 2; ++ct)
        #pragma unroll
        for (int r = 0; r < 4; ++r) o[ct][r] = 0.f;

    for (int s = 0; s < 18; ++s) {
        int cm = s * 4 + q;
        v8s a = *(const v8s*)&P[l15 * 576 + ((cm ^ (l15 & 7)) << 3)];
        #pragma unroll
        for (int ct = 0; ct < 2; ++ct) {
            int ctile = wave * 2 + ct;
            v8s b = *(const v8s*)(Vp + ((size_t)(ctile * 18 + s)) * 512 + lane * 8);
            o[ct] = __builtin_amdgcn_mfma_f32_16x16x32_bf16(a, b, o[ct], 0, 0, 0);
        }
    }

    #pragma unroll
    for (int ct = 0; ct < 2; ++ct) {
        int c = (wave * 2 + ct) * 16 + l15;
        size_t base = ((size_t)p * 128 + c) * 576 + n0 + q * 4;
        if (MODE == 0) {
            float al = alpha[0];
            #pragma unroll
            for (int r = 0; r < 4; ++r)
                Of[base + r] = al * o[ct][r] * inv[r] + addsrc[base + r];
        } else {
            #pragma unroll
            for (int r = 0; r < 4; ++r)
                Oh[base + r] = f2bf(o[ct][r] * inv[r]);
        }
    }
}

// --------------------------- fused window-sum + gate (one block per pair)
__global__ __launch_bounds__(256) void wsum_g_kernel(
    const unsigned short* __restrict__ mji, const float* __restrict__ Wg,
    const float* __restrict__ Wgb, float* __restrict__ g)
{
    __shared__ float sw[128 * 9];
    int pair = blockIdx.x;
    int t = threadIdx.x, wave = t >> 6, lane = t & 63;
    #pragma unroll 1
    for (int k = 0; k < 32; ++k) {
        int ci = wave * 32 + k;
        const unsigned short* p = mji + ((size_t)pair * C_ + ci) * N_;
        float T=0, R0=0, R23=0, Cl=0, Cr=0, c00=0, c0w=0, ch0=0, chw=0;
        for (int i = lane; i < N_; i += 64) {
            float v = bf2f(p[i]);
            int r = i / 24, cc = i % 24;
            T += v;
            if (r == 0)  R0  += v;
            if (r == 23) R23 += v;
            if (cc == 0)  Cl += v;
            if (cc == 23) Cr += v;
            if (i == 0)   c00 = v;
            if (i == 23)  c0w = v;
            if (i == 552) ch0 = v;
            if (i == 575) chw = v;
        }
        #pragma unroll
        for (int off = 32; off > 0; off >>= 1) {
            T  += __shfl_xor(T, off);  R0 += __shfl_xor(R0, off);  R23 += __shfl_xor(R23, off);
            Cl += __shfl_xor(Cl, off); Cr += __shfl_xor(Cr, off);
            c00 += __shfl_xor(c00, off); c0w += __shfl_xor(c0w, off);
            ch0 += __shfl_xor(ch0, off); chw += __shfl_xor(chw, off);
        }
        if (lane == 0) {
            float rowsub[3] = {R23, 0.f, R0};
            float colsub[3] = {Cr,  0.f, Cl};
            float corner[9] = {chw, 0.f, ch0,  0.f, 0.f, 0.f,  c0w, 0.f, c00};
            #pragma unroll
            for (int ky = 0; ky < 3; ++ky)
                #pragma unroll
                for (int kx = 0; kx < 3; ++kx)
                    sw[ci * 9 + ky * 3 + kx] = T - rowsub[ky] - colsub[kx] + corner[ky * 3 + kx];
        }
    }
    __syncthreads();
    if (t < 128) {
        const float* w = Wg + (size_t)t * C_ * 9;
        float acc = 0.f;
        for (int i = 0; i < C_ * 9; ++i) acc += w[i] * sw[i];
        float m = acc * (1.f / 576.f) + Wgb[t];
        g[pair * C_ + t] = 1.f / (1.f + __expf(-m));
    }
}

// ----------------------- fused msg compute + transpose-cast -> msgT16 [px][c]
__global__ __launch_bounds__(256) void msg_tc_kernel(
    const float* __restrict__ eii, const unsigned short* __restrict__ mji,
    const float* __restrict__ g, const float* __restrict__ bn_gamma,
    const float* __restrict__ bn_beta, const float* __restrict__ intra_w,
    const float* __restrict__ inter_w, unsigned short* __restrict__ msgT)
{
    __shared__ float tile[128][65];
    int img = blockIdx.y, px0 = blockIdx.x * 64, t = threadIdx.x;
    int s = img >> 1, b = img & 1;
    float iw = intra_w[0], ew = inter_w[0];
    #pragma unroll
    for (int i = 0; i < 32; ++i) {
        int e = i * 256 + t; int ci = e >> 6; int pxl = e & 63;
        int px = px0 + pxl;
        float scale = bn_gamma[ci] * rsqrtf(1.f + 1e-5f);
        float acc = 0.f;
        #pragma unroll
        for (int jj = 0; jj < 4; ++jj) {
            int pidx = (s * 4 + jj) * 2 + b;
            acc += g[pidx * C_ + ci] * bf2f(mji[((size_t)pidx * C_ + ci) * N_ + px]);
        }
        float inter = scale * acc + 4.f * bn_beta[ci];
        tile[ci][pxl] = iw * eii[((size_t)img * C_ + ci) * N_ + px] + ew * inter;
    }
    __syncthreads();
    #pragma unroll
    for (int i = 0; i < 32; ++i) {
        int e = i * 256 + t; int pxl = e >> 7; int ci = e & 127;
        msgT[((size_t)img * 576 + px0 + pxl) * 128 + ci] = f2bf(tile[ci][pxl]);
    }
}

// -------- fused GRU update + next-iter transpose/packs (hT [px][c], VF pack)
__global__ __launch_bounds__(256) void update_tc_kernel(
    const float* __restrict__ zrp, const float* __restrict__ zrb,
    const float* __restrict__ hhp, const float* __restrict__ ghb,
    const float* __restrict__ h, float* __restrict__ out,
    unsigned short* __restrict__ hTn, unsigned short* __restrict__ VFn, int last)
{
    const size_t ZP = (size_t)SB * C2 * N_;
    const size_t HP = (size_t)SB * C_ * N_;
    __shared__ float tile[128][65];
    int img = blockIdx.y, px0 = blockIdx.x * 64, t = threadIdx.x;
    #pragma unroll
    for (int i = 0; i < 32; ++i) {
        int e = i * 256 + t; int ci = e >> 6; int pxl = e & 63;
        int px = px0 + pxl;
        size_t zi = ((size_t)img * C2 + ci) * N_ + px;
        float za = zrb[ci];
        #pragma unroll
        for (int k = 0; k < 4; ++k) za += zrp[k * ZP + zi];
        float z = 1.f / (1.f + __expf(-za));
        size_t hi = ((size_t)img * C_ + ci) * N_ + px;
        float ha = ghb[ci];
        #pragma unroll
        for (int k = 0; k < 4; ++k) ha += hhp[k * HP + hi];
        float hh = tanhf(ha);
        float o = (2.f - z) * h[hi] + z * hh;
        out[hi] = o;
        tile[ci][pxl] = o;
        if (!last) {
            int ctile = ci >> 4, l15v = ci & 15;
            int sIdx = px >> 5, quadv = (px >> 3) & 3, j = px & 7;
            VFn[(((size_t)img * 8 + ctile) * 18 + sIdx) * 512 + (quadv * 16 + l15v) * 8 + j] = f2bf(o);
        }
    }
    if (!last) {
        __syncthreads();
        #pragma unroll
        for (int i = 0; i < 32; ++i) {
            int e = i * 256 + t; int pxl = e >> 7; int ci = e & 127;
            hTn[((size_t)img * 576 + px0 + pxl) * 128 + ci] = f2bf(tile[ci][pxl]);
        }
    }
}

// ------------------------------------------------------------------- launcher
extern "C" void kernel_launch(void* const* d_in, const int* in_sizes, int n_in,
                              void* d_out, int out_size, void* d_ws, size_t ws_size,
                              hipStream_t stream)
{
    const float* x      = (const float*)d_in[0];
    const float* Wf_w   = (const float*)d_in[1];
    const float* Wf_b   = (const float*)d_in[2];
    const float* Wh_w   = (const float*)d_in[3];
    const float* Wh_b   = (const float*)d_in[4];
    const float* Wl_w   = (const float*)d_in[5];
    const float* Wl_b   = (const float*)d_in[6];
    const float* alpha  = (const float*)d_in[7];
    const float* Wc     = (const float*)d_in[8];
    const float* Wg_w   = (const float*)d_in[9];
    const float* Wg_b   = (const float*)d_in[10];
    const float* bng    = (const float*)d_in[11];
    const float* bnb    = (const float*)d_in[12];
    const float* zr_w   = (const float*)d_in[13];
    const float* zr_b   = (const float*)d_in[14];
    const float* gh_w   = (const float*)d_in[15];
    const float* gh_b   = (const float*)d_in[16];
    const float* intraw = (const float*)d_in[17];
    const float* interw = (const float*)d_in[18];
    float* outp = (float*)d_out;

    float* f = (float*)d_ws;
    const size_t SZ = (size_t)SB * C_ * N_;
    float* hbuf  = f; f += SZ;
    float* eii   = f; f += SZ;
    float* zrp   = f; f += 4 * (size_t)SB * C2 * N_;
    float* hhp   = f; f += 4 * SZ;
    float* gbuf  = f; f += (size_t)NPAIR * C_;
    unsigned short* us = (unsigned short*)f;
    unsigned short* mji16  = us; us += (size_t)NPAIR * C_ * N_;
    unsigned short* hT16   = us; us += SZ;
    unsigned short* hc16   = us; us += SZ;           // VFi inter / rhbT16
    unsigned short* msgT16 = us; us += SZ;
    unsigned short* ftT    = us; us += SZ;           // Q intra / KFi inter
    unsigned short* KFa    = us; us += SZ;
    unsigned short* VFa    = us; us += SZ;
    unsigned short* Wp3    = us; us += (size_t)384 * 1152;
    unsigned short* Wpzr   = us; us += (size_t)256 * 6400;
    unsigned short* Wph    = us; us += (size_t)128 * 6400;
    unsigned short* Wcb    = us; us += (size_t)128 * 128;

    unsigned short* KFi    = ftT;
    unsigned short* VFi    = hc16;
    unsigned short* rhbT16 = hc16;

    packA3_kernel<<<(384 * 1152 + 255) / 256, 256, 0, stream>>>(Wf_w, Wh_w, Wl_w, Wp3);
    packA5_kernel<<<(256 * 6400 + 255) / 256, 256, 0, stream>>>(zr_w, Wpzr, 256);
    packA5_kernel<<<(128 * 6400 + 255) / 256, 256, 0, stream>>>(gh_w, Wph, 128);
    packWc_kernel<<<64, 256, 0, stream>>>(Wc, Wcb);

    // initial transpose/packs from x
    tc_kernel<<<dim3(9, SB), 256, 0, stream>>>(x, nullptr, nullptr, hT16, VFi);

    const float* hcur = x;
    for (int it = 0; it < 3; ++it) {
        float* hout = (it == 2) ? outp : hbuf;

        conv_mfma<3, 1, 128, 1, 1><<<dim3(6, 3, SB), 256, 0, stream>>>(
            hT16, hT16, Wp3, 384, nullptr, Wf_b, Wh_b, Wl_b, ftT, KFa, VFa);
        attn_mfma<0><<<dim3(36, SB), 256, 0, stream>>>(ftT, KFa, VFa, eii, nullptr, hcur, alpha);
        yt_mfma<<<dim3(36, SB), 256, 0, stream>>>(hT16, Wcb, KFi);
        attn_mfma<1><<<dim3(36, NPAIR), 256, 0, stream>>>(hT16, KFi, VFi, nullptr, mji16, nullptr, nullptr);
        wsum_g_kernel<<<NPAIR, 256, 0, stream>>>(mji16, Wg_w, Wg_b, gbuf);
        msg_tc_kernel<<<dim3(9, SB), 256, 0, stream>>>(eii, mji16, gbuf, bng, bnb, intraw, interw, msgT16);
        conv_mfma<5, 2, 256, 4, 0><<<dim3(16, 3, SB), 256, 0, stream>>>(
            msgT16, hT16, Wpzr, 256, zrp, nullptr, nullptr, nullptr, nullptr, nullptr, nullptr);
        tc_kernel<<<dim3(9, SB), 256, 0, stream>>>(hcur, zrp, zr_b, rhbT16, nullptr);
        conv_mfma<5, 2, 256, 4, 0><<<dim3(8, 3, SB), 256, 0, stream>>>(
            msgT16, rhbT16, Wph, 128, hhp, nullptr, nullptr, nullptr, nullptr, nullptr, nullptr);
        update_tc_kernel<<<dim3(9, SB), 256, 0, stream>>>(
            zrp, zr_b, hhp, gh_b, hcur, hout, hT16, VFi, (it == 2) ? 1 : 0);
        hcur = hout;
    }
}

// Round 12
// 888.908 us; speedup vs baseline: 1.0800x; 1.0800x over previous
//
#include <hip/hip_runtime.h>
#include <math.h>

#define S_  5
#define B_  2
#define C_  128
#define N_  576
#define SB  10
#define NPAIR 40
#define C2  256

typedef short v8s __attribute__((ext_vector_type(8)));
typedef float v4f __attribute__((ext_vector_type(4)));

#define GLOBAL_AS __attribute__((address_space(1)))
#define LDS_AS    __attribute__((address_space(3)))

__device__ __forceinline__ unsigned short f2bf(float f) {
    union { float f; unsigned u; } v; v.f = f;
    unsigned r = (v.u + 0x7FFF + ((v.u >> 16) & 1)) >> 16;
    return (unsigned short)r;
}
__device__ __forceinline__ float bf2f(unsigned short h) {
    union { unsigned u; float f; } v; v.u = ((unsigned)h) << 16;
    return v.f;
}

// ------------------------------------------------------------------ weight packs
// Fragment-major A: [cgb][kk][ch][g][tap_l][c(4)][l15(16)][quad(4)][j(8)]
__global__ void packA5_kernel(const float* __restrict__ w, unsigned short* __restrict__ Apk, int M)
{
    int idx = blockIdx.x * 256 + threadIdx.x;
    if (idx >= M * 6400) return;
    int r = idx;
    int j = r & 7;      r >>= 3;
    int quad = r & 3;   r >>= 2;
    int l15 = r & 15;   r >>= 4;
    int c = r & 3;      r >>= 2;
    int tap_l = r % 5;  r /= 5;
    int g = r % 5;      r /= 5;
    int ch = r & 1;     r >>= 1;
    int kk = r & 3;     r >>= 2;
    int cgb = r;
    int co = cgb * 64 + c * 16 + l15;
    int ci = kk * 64 + ch * 32 + quad * 8 + j;
    int tap = g * 5 + tap_l;
    Apk[idx] = f2bf(w[((size_t)co * 256 + ci) * 25 + tap]);
}
__global__ void packA3_kernel(const float* __restrict__ wf, const float* __restrict__ wh,
                              const float* __restrict__ wl, unsigned short* __restrict__ Apk)
{
    int idx = blockIdx.x * 256 + threadIdx.x;
    if (idx >= 384 * 1152) return;
    int r = idx;
    int j = r & 7;      r >>= 3;
    int quad = r & 3;   r >>= 2;
    int l15 = r & 15;   r >>= 4;
    int c = r & 3;      r >>= 2;
    int tap_l = r % 3;  r /= 3;
    int g = r % 3;      r /= 3;
    int ch = r & 1;     r >>= 1;
    int kk = r & 1;     r >>= 1;
    int cgb = r;
    int co = cgb * 64 + c * 16 + l15;
    const float* w = (co < 128) ? wf : (co < 256) ? wh : wl;
    int cl = co & 127;
    int ci = kk * 64 + ch * 32 + quad * 8 + j;
    int tap = g * 3 + tap_l;
    Apk[idx] = f2bf(w[((size_t)cl * 128 + ci) * 9 + tap]);
}
__global__ void packWc_kernel(const float* __restrict__ w, unsigned short* __restrict__ o)
{
    int idx = blockIdx.x * 256 + threadIdx.x;
    if (idx < 128 * 128) o[idx] = f2bf(w[idx]);
}

// ---------------------------------------------- transpose-cast (x at it=0, rhb)
// zrp != null: multiply by r = sigmoid(sum_{k<4} zrp[k][128+c] + zrb[128+c])
// vfd != null: also emit V-fragment-packed bf16
__global__ __launch_bounds__(256) void tc_kernel(
    const float* __restrict__ src, const float* __restrict__ zrp,
    const float* __restrict__ zrb,
    unsigned short* __restrict__ dst, unsigned short* __restrict__ vfd)
{
    const size_t PLANE = (size_t)SB * C2 * N_;
    __shared__ float tile[128][65];
    int img = blockIdx.y, px0 = blockIdx.x * 64, t = threadIdx.x;
    #pragma unroll
    for (int i = 0; i < 32; ++i) {
        int e = i * 256 + t; int ci = e >> 6; int px = e & 63;
        float v = src[((size_t)img * 128 + ci) * 576 + px0 + px];
        if (zrp) {
            size_t zi = ((size_t)img * C2 + 128 + ci) * 576 + px0 + px;
            float a = zrb[128 + ci];
            #pragma unroll
            for (int k = 0; k < 4; ++k) a += zrp[k * PLANE + zi];
            v *= 1.f / (1.f + __expf(-a));
        }
        tile[ci][px] = v;
        if (vfd) {
            int m = px0 + px;
            int ctile = ci >> 4, l15v = ci & 15;
            int sIdx = m >> 5, quadv = (m >> 3) & 3, j = m & 7;
            vfd[(((size_t)img * 8 + ctile) * 18 + sIdx) * 512 + (quadv * 16 + l15v) * 8 + j] = f2bf(v);
        }
    }
    __syncthreads();
    #pragma unroll
    for (int i = 0; i < 32; ++i) {
        int e = i * 256 + t; int px = e >> 7; int ci = e & 127;
        dst[((size_t)img * 576 + px0 + px) * 128 + ci] = f2bf(tile[ci][px]);
    }
}

// ------------------------------------------------------ MFMA implicit-GEMM conv v7
// MODE 0: f32 partial planes per kk (5x5 convs, SPLITK=4)
// MODE 1: conv3 full-K fused epilogue: +bias, write ftT(Q) / KFa(K-pack) / VFa(V-pack)
template<int KD, int R, int CINT, int SPLITK, int MODE>
__global__ __launch_bounds__(256, 1) void conv_mfma(
    const unsigned short* __restrict__ srcA, const unsigned short* __restrict__ srcB,
    const unsigned short* __restrict__ Apk, int COUT, float* __restrict__ po,
    const float* __restrict__ b0, const float* __restrict__ b1, const float* __restrict__ b2,
    unsigned short* __restrict__ t0, unsigned short* __restrict__ t1,
    unsigned short* __restrict__ t2)
{
    constexpr int PART   = CINT / SPLITK;
    constexpr int NCH    = PART / 32;
    constexpr int NSUB   = NCH * KD;
    constexpr int WR     = 8 + 2 * R;
    constexpr int WC     = 24 + 2 * R;
    constexpr int NPOS   = WR * WC;
    constexpr int NSLOTB = NPOS * 4;
    constexpr int RB     = (NSLOTB + 255) / 256;
    constexpr int AUNITS = KD * 4 * 64;
    constexpr int AR     = AUNITS / 256;
    __shared__ __align__(16) unsigned short Ab[2][AUNITS * 8];
    __shared__ __align__(16) unsigned short Bb[NPOS * 32];

    int f   = blockIdx.x;
    int kk  = f % SPLITK;
    int cgb = f / SPLITK;
    int pxb = blockIdx.y;
    int img = blockIdx.z;
    int t = threadIdx.x;
    int wave = t >> 6, lane = t & 63;
    int quad = lane >> 4, l15 = lane & 15;
    int r0 = pxb * 8;

    const int cibase = kk * PART;
    const unsigned short* src = (cibase >= 128) ? srcB : srcA;
    const int cioff0 = cibase & 127;
    const unsigned short* srcI = src + (size_t)img * 576 * 128;

    int posBase[3], pxs[3];
    #pragma unroll
    for (int s = 0; s < 3; ++s) {
        int px = pxb * 192 + wave * 48 + s * 16 + l15;
        pxs[s] = px;
        int pr = px / 24, pc = px % 24;
        posBase[s] = (pr - r0 + R) * WC + pc + R;
    }

    int goffB[RB]; bool gokB[RB];
    #pragma unroll
    for (int rr = 0; rr < RB; ++rr) {
        int idx = rr * 256 + wave * 64 + lane;
        int pos = idx >> 2, slotq = idx & 3;
        int gr = slotq ^ ((pos >> 1) & 3);
        int wr = pos / WC, wc = pos % WC;
        int grow = r0 - R + wr, gcol = wc - R;
        gokB[rr] = (idx < NSLOTB) && grow >= 0 && grow < 24 && gcol >= 0 && gcol < 24;
        goffB[rr] = (grow * 24 + gcol) * 128 + gr * 8;
    }

    auto stageB = [&](int ch) {
        const unsigned short* sp = srcI + cioff0 + ch * 32;
        #pragma unroll
        for (int rr = 0; rr < RB; ++rr) {
            if (gokB[rr]) {
                __builtin_amdgcn_global_load_lds(
                    (const GLOBAL_AS void*)(sp + goffB[rr]),
                    (LDS_AS void*)((char*)&Bb[0] + (size_t)(rr * 256 + wave * 64) * 16),
                    16, 0, 0);
            }
        }
    };
    auto stageA = [&](int sub, int buf) {
        const unsigned short* sp = Apk + ((size_t)((cgb * SPLITK + kk) * NSUB + sub)) * (AUNITS * 8);
        #pragma unroll
        for (int r = 0; r < AR; ++r) {
            int u0 = r * 256 + wave * 64;
            __builtin_amdgcn_global_load_lds(
                (const GLOBAL_AS void*)(sp + (size_t)(u0 + lane) * 8),
                (LDS_AS void*)((char*)&Ab[buf][0] + (size_t)u0 * 16),
                16, 0, 0);
        }
    };

    v4f acc[4][3];
    #pragma unroll
    for (int c = 0; c < 4; ++c)
        #pragma unroll
        for (int s = 0; s < 3; ++s)
            #pragma unroll
            for (int r = 0; r < 4; ++r) acc[c][s][r] = 0.f;

    {
        v8s zv;
        #pragma unroll
        for (int j = 0; j < 8; ++j) zv[j] = 0;
        for (int i = t; i < NPOS * 4; i += 256) ((v8s*)Bb)[i] = zv;
    }
    __syncthreads();
    stageB(0);
    stageA(0, 0);
    __syncthreads();

    int sub = 0;
    #pragma unroll 1
    for (int ch = 0; ch < NCH; ++ch) {
        #pragma unroll 1
        for (int g = 0; g < KD; ++g) {
            if (sub + 1 < NSUB) stageA(sub + 1, (sub + 1) & 1);
            const unsigned short* Ap = &Ab[sub & 1][0];
            #pragma unroll
            for (int tl = 0; tl < KD; ++tl) {
                int doff = (g - R) * WC + (tl - R);
                v8s a[4];
                #pragma unroll
                for (int c = 0; c < 4; ++c)
                    a[c] = *(const v8s*)&Ap[((tl * 4 + c) * 64 + l15 * 4 + quad) * 8];
                v8s b[3];
                #pragma unroll
                for (int s = 0; s < 3; ++s) {
                    int pos = posBase[s] + doff;
                    b[s] = *(const v8s*)&Bb[pos * 32 + ((quad ^ ((pos >> 1) & 3)) << 3)];
                }
                #pragma unroll
                for (int c = 0; c < 4; ++c)
                    #pragma unroll
                    for (int s = 0; s < 3; ++s)
                        acc[c][s] = __builtin_amdgcn_mfma_f32_16x16x32_bf16(a[c], b[s], acc[c][s], 0, 0, 0);
            }
            __syncthreads();
            ++sub;
        }
        if (ch + 1 < NCH) { stageB(ch + 1); __syncthreads(); }
    }

    if (MODE == 0) {
        float* out = po + (size_t)kk * ((size_t)SB * COUT * 576)
                   + ((size_t)img * COUT + cgb * 64) * 576;
        #pragma unroll
        for (int c = 0; c < 4; ++c)
            #pragma unroll
            for (int s = 0; s < 3; ++s)
                #pragma unroll
                for (int r = 0; r < 4; ++r) {
                    int col = c * 16 + quad * 4 + r;
                    out[(size_t)col * 576 + pxs[s]] = acc[c][s][r];
                }
    } else {
        #pragma unroll
        for (int c = 0; c < 4; ++c)
            #pragma unroll
            for (int s = 0; s < 3; ++s) {
                int px = pxs[s];
                #pragma unroll
                for (int r = 0; r < 4; ++r) {
                    int co = cgb * 64 + c * 16 + quad * 4 + r;
                    int which = co >> 7, cl = co & 127;
                    const float* bp = (which == 0) ? b0 : (which == 1) ? b1 : b2;
                    float v = acc[c][s][r] + bp[cl];
                    if (which == 0) {
                        t0[((size_t)img * 576 + px) * 128 + cl] = f2bf(v);
                    } else if (which == 1) {
                        int mt = px >> 4, l15m = px & 15;
                        int kb = cl >> 5, quadk = (cl >> 3) & 3, jj = cl & 7;
                        t1[(((size_t)img * 36 + mt) * 4 + kb) * 512 + (quadk * 16 + l15m) * 8 + jj] = f2bf(v);
                    } else {
                        int ctile = cl >> 4, l15v = cl & 15;
                        int sIdx = px >> 5, quadv = (px >> 3) & 3, jj = px & 7;
                        t2[(((size_t)img * 8 + ctile) * 18 + sIdx) * 512 + (quadv * 16 + l15v) * 8 + jj] = f2bf(v);
                    }
                }
            }
    }
}

// ---------------------------------------------------------------- yt (MFMA) -> K-packed
__global__ __launch_bounds__(256) void yt_mfma(
    const unsigned short* __restrict__ hT, const unsigned short* __restrict__ Wcb,
    unsigned short* __restrict__ KFi)
{
    int t = threadIdx.x, wave = t >> 6, lane = t & 63;
    int q = lane >> 4, l15 = lane & 15;
    int n0 = blockIdx.x * 16, img = blockIdx.y;
    v4f acc[2];
    #pragma unroll
    for (int ct = 0; ct < 2; ++ct)
        #pragma unroll
        for (int r = 0; r < 4; ++r) acc[ct][r] = 0.f;
    #pragma unroll
    for (int kk = 0; kk < 4; ++kk) {
        v8s b = *(const v8s*)(hT + ((size_t)img * 576 + n0 + l15) * 128 + kk * 32 + q * 8);
        #pragma unroll
        for (int ct = 0; ct < 2; ++ct) {
            v8s a = *(const v8s*)(Wcb + (size_t)((wave * 2 + ct) * 16 + l15) * 128 + kk * 32 + q * 8);
            acc[ct] = __builtin_amdgcn_mfma_f32_16x16x32_bf16(a, b, acc[ct], 0, 0, 0);
        }
    }
    int mt = blockIdx.x;
    #pragma unroll
    for (int ct = 0; ct < 2; ++ct) {
        #pragma unroll
        for (int r = 0; r < 4; ++r) {
            int co = (wave * 2 + ct) * 16 + q * 4 + r;
            int kk = co >> 5, quadk = (co >> 3) & 3, j = co & 7;
            KFi[(((size_t)img * 36 + mt) * 4 + kk) * 512 + (quadk * 16 + l15) * 8 + j]
                = f2bf(acc[ct][r]);
        }
    }
}

// ---------------------------------------------------- MFMA flash attention
template<int MODE>
__global__ __launch_bounds__(256) void attn_mfma(
    const unsigned short* __restrict__ QT, const unsigned short* __restrict__ KF,
    const unsigned short* __restrict__ VF, float* __restrict__ Of,
    unsigned short* __restrict__ Oh, const float* __restrict__ addsrc,
    const float* __restrict__ alpha)
{
    __shared__ __align__(16) unsigned short P[16 * 576];
    __shared__ float redmx[4][16];
    __shared__ float redsm[4][16];
    int t = threadIdx.x;
    int wave = t >> 6, lane = t & 63;
    int q = lane >> 4, l15 = lane & 15;
    int n0 = blockIdx.x * 16;
    int p = blockIdx.y;
    int qimg, kimg;
    if (MODE == 0) { qimg = p; kimg = p; }
    else {
        int b = p & 1; int ij = p >> 1; int i = ij >> 2; int jj = ij & 3;
        int j = jj + (jj >= i ? 1 : 0);
        qimg = i * 2 + b; kimg = j * 2 + b;
    }
    const unsigned short* Qp = QT + ((size_t)qimg * 576 + n0) * 128;
    const unsigned short* Kp = KF + (size_t)kimg * 36 * 4 * 512;
    const unsigned short* Vp = VF + (size_t)kimg * 8 * 18 * 512;

    v8s aq[4];
    #pragma unroll
    for (int kk = 0; kk < 4; ++kk)
        aq[kk] = *(const v8s*)(Qp + (size_t)l15 * 128 + kk * 32 + q * 8);

    v4f S[9];
    #pragma unroll
    for (int i = 0; i < 9; ++i)
        #pragma unroll
        for (int r = 0; r < 4; ++r) S[i][r] = 0.f;

    #pragma unroll
    for (int i = 0; i < 9; ++i) {
        int mt = wave * 9 + i;
        #pragma unroll
        for (int kk = 0; kk < 4; ++kk) {
            v8s b = *(const v8s*)(Kp + ((size_t)(mt * 4 + kk)) * 512 + lane * 8);
            S[i] = __builtin_amdgcn_mfma_f32_16x16x32_bf16(aq[kk], b, S[i], 0, 0, 0);
        }
    }

    float mx[4];
    #pragma unroll
    for (int r = 0; r < 4; ++r) {
        float m = S[0][r];
        #pragma unroll
        for (int i = 1; i < 9; ++i) m = fmaxf(m, S[i][r]);
        #pragma unroll
        for (int off = 1; off < 16; off <<= 1) m = fmaxf(m, __shfl_xor(m, off));
        mx[r] = m;
    }
    if (l15 == 0) {
        #pragma unroll
        for (int r = 0; r < 4; ++r) redmx[wave][q * 4 + r] = mx[r];
    }
    __syncthreads();
    float sum[4];
    #pragma unroll
    for (int r = 0; r < 4; ++r) {
        float g = fmaxf(fmaxf(redmx[0][q * 4 + r], redmx[1][q * 4 + r]),
                        fmaxf(redmx[2][q * 4 + r], redmx[3][q * 4 + r]));
        float s = 0.f;
        #pragma unroll
        for (int i = 0; i < 9; ++i) { float e = __expf(S[i][r] - g); S[i][r] = e; s += e; }
        #pragma unroll
        for (int off = 1; off < 16; off <<= 1) s += __shfl_xor(s, off);
        sum[r] = s;
    }
    if (l15 == 0) {
        #pragma unroll
        for (int r = 0; r < 4; ++r) redsm[wave][q * 4 + r] = sum[r];
    }
    #pragma unroll
    for (int i = 0; i < 9; ++i) {
        int m = (wave * 9 + i) * 16 + l15;
        int cm = m >> 3, mo = m & 7;
        #pragma unroll
        for (int r = 0; r < 4; ++r) {
            int n = q * 4 + r;
            P[n * 576 + ((cm ^ (n & 7)) << 3) + mo] = f2bf(S[i][r]);
        }
    }
    __syncthreads();
    float inv[4];
    #pragma unroll
    for (int r = 0; r < 4; ++r)
        inv[r] = 1.f / (redsm[0][q * 4 + r] + redsm[1][q * 4 + r] +
                        redsm[2][q * 4 + r] + redsm[3][q * 4 + r]);

    v4f o[2];
    #pragma unroll
    for (int ct = 0; ct < 2; ++ct)
        #pragma unroll
        for (int r = 0; r < 4; ++r) o[ct][r] = 0.f;

    for (int s = 0; s < 18; ++s) {
        int cm = s * 4 + q;
        v8s a = *(const v8s*)&P[l15 * 576 + ((cm ^ (l15 & 7)) << 3)];
        #pragma unroll
        for (int ct = 0; ct < 2; ++ct) {
            int ctile = wave * 2 + ct;
            v8s b = *(const v8s*)(Vp + ((size_t)(ctile * 18 + s)) * 512 + lane * 8);
            o[ct] = __builtin_amdgcn_mfma_f32_16x16x32_bf16(a, b, o[ct], 0, 0, 0);
        }
    }

    #pragma unroll
    for (int ct = 0; ct < 2; ++ct) {
        int c = (wave * 2 + ct) * 16 + l15;
        size_t base = ((size_t)p * 128 + c) * 576 + n0 + q * 4;
        if (MODE == 0) {
            float al = alpha[0];
            #pragma unroll
            for (int r = 0; r < 4; ++r)
                Of[base + r] = al * o[ct][r] * inv[r] + addsrc[base + r];
        } else {
            #pragma unroll
            for (int r = 0; r < 4; ++r)
                Oh[base + r] = f2bf(o[ct][r] * inv[r]);
        }
    }
}

// ------------------------------------- window sums for analytic gate-conv mean
__global__ __launch_bounds__(64) void wsum_kernel(
    const unsigned short* __restrict__ mji, float* __restrict__ wsum)
{
    int pair = blockIdx.x, ci = blockIdx.y, lane = threadIdx.x;
    const unsigned short* p = mji + ((size_t)pair * C_ + ci) * N_;
    float T=0, R0=0, R23=0, Cl=0, Cr=0, c00=0, c0w=0, ch0=0, chw=0;
    for (int i = lane; i < N_; i += 64) {
        float v = bf2f(p[i]);
        int r = i / 24, cc = i % 24;
        T += v;
        if (r == 0)  R0  += v;
        if (r == 23) R23 += v;
        if (cc == 0)  Cl += v;
        if (cc == 23) Cr += v;
        if (i == 0)   c00 = v;
        if (i == 23)  c0w = v;
        if (i == 552) ch0 = v;
        if (i == 575) chw = v;
    }
    #pragma unroll
    for (int off = 32; off > 0; off >>= 1) {
        T  += __shfl_xor(T, off);  R0 += __shfl_xor(R0, off);  R23 += __shfl_xor(R23, off);
        Cl += __shfl_xor(Cl, off); Cr += __shfl_xor(Cr, off);
        c00 += __shfl_xor(c00, off); c0w += __shfl_xor(c0w, off);
        ch0 += __shfl_xor(ch0, off); chw += __shfl_xor(chw, off);
    }
    if (lane == 0) {
        float rowsub[3] = {R23, 0.f, R0};
        float colsub[3] = {Cr,  0.f, Cl};
        float corner[9] = {chw, 0.f, ch0,  0.f, 0.f, 0.f,  c0w, 0.f, c00};
        float* o = wsum + ((size_t)pair * C_ + ci) * 9;
        #pragma unroll
        for (int ky = 0; ky < 3; ++ky)
            #pragma unroll
            for (int kx = 0; kx < 3; ++kx)
                o[ky * 3 + kx] = T - rowsub[ky] - colsub[kx] + corner[ky * 3 + kx];
    }
}

__global__ __launch_bounds__(128) void g_kernel(
    const float* __restrict__ wsum, const float* __restrict__ Wg,
    const float* __restrict__ Wgb, float* __restrict__ g)
{
    __shared__ float sw[C_ * 9];
    int pair = blockIdx.x; int co = threadIdx.x;
    for (int i = co; i < C_ * 9; i += 128) sw[i] = wsum[(size_t)pair * C_ * 9 + i];
    __syncthreads();
    const float* w = Wg + (size_t)co * C_ * 9;
    float acc = 0.f;
    for (int i = 0; i < C_ * 9; ++i) acc += w[i] * sw[i];
    float m = acc * (1.f / 576.f) + Wgb[co];
    g[pair * C_ + co] = 1.f / (1.f + __expf(-m));
}

// ----------------------- fused msg compute + transpose-cast -> msgT16 [px][c]
__global__ __launch_bounds__(256) void msg_tc_kernel(
    const float* __restrict__ eii, const unsigned short* __restrict__ mji,
    const float* __restrict__ g, const float* __restrict__ bn_gamma,
    const float* __restrict__ bn_beta, const float* __restrict__ intra_w,
    const float* __restrict__ inter_w, unsigned short* __restrict__ msgT)
{
    __shared__ float tile[128][65];
    int img = blockIdx.y, px0 = blockIdx.x * 64, t = threadIdx.x;
    int s = img >> 1, b = img & 1;
    float iw = intra_w[0], ew = inter_w[0];
    #pragma unroll
    for (int i = 0; i < 32; ++i) {
        int e = i * 256 + t; int ci = e >> 6; int pxl = e & 63;
        int px = px0 + pxl;
        float scale = bn_gamma[ci] * rsqrtf(1.f + 1e-5f);
        float acc = 0.f;
        #pragma unroll
        for (int jj = 0; jj < 4; ++jj) {
            int pidx = (s * 4 + jj) * 2 + b;
            acc += g[pidx * C_ + ci] * bf2f(mji[((size_t)pidx * C_ + ci) * N_ + px]);
        }
        float inter = scale * acc + 4.f * bn_beta[ci];
        tile[ci][pxl] = iw * eii[((size_t)img * C_ + ci) * N_ + px] + ew * inter;
    }
    __syncthreads();
    #pragma unroll
    for (int i = 0; i < 32; ++i) {
        int e = i * 256 + t; int pxl = e >> 7; int ci = e & 127;
        msgT[((size_t)img * 576 + px0 + pxl) * 128 + ci] = f2bf(tile[ci][pxl]);
    }
}

// -------- fused GRU update + next-iter transpose/packs (hT [px][c], VF pack)
__global__ __launch_bounds__(256) void update_tc_kernel(
    const float* __restrict__ zrp, const float* __restrict__ zrb,
    const float* __restrict__ hhp, const float* __restrict__ ghb,
    const float* __restrict__ h, float* __restrict__ out,
    unsigned short* __restrict__ hTn, unsigned short* __restrict__ VFn, int last)
{
    const size_t ZP = (size_t)SB * C2 * N_;
    const size_t HP = (size_t)SB * C_ * N_;
    __shared__ float tile[128][65];
    int img = blockIdx.y, px0 = blockIdx.x * 64, t = threadIdx.x;
    #pragma unroll
    for (int i = 0; i < 32; ++i) {
        int e = i * 256 + t; int ci = e >> 6; int pxl = e & 63;
        int px = px0 + pxl;
        size_t zi = ((size_t)img * C2 + ci) * N_ + px;
        float za = zrb[ci];
        #pragma unroll
        for (int k = 0; k < 4; ++k) za += zrp[k * ZP + zi];
        float z = 1.f / (1.f + __expf(-za));
        size_t hi = ((size_t)img * C_ + ci) * N_ + px;
        float ha = ghb[ci];
        #pragma unroll
        for (int k = 0; k < 4; ++k) ha += hhp[k * HP + hi];
        float hh = tanhf(ha);
        float o = (2.f - z) * h[hi] + z * hh;
        out[hi] = o;
        tile[ci][pxl] = o;
        if (!last) {
            int ctile = ci >> 4, l15v = ci & 15;
            int sIdx = px >> 5, quadv = (px >> 3) & 3, j = px & 7;
            VFn[(((size_t)img * 8 + ctile) * 18 + sIdx) * 512 + (quadv * 16 + l15v) * 8 + j] = f2bf(o);
        }
    }
    if (!last) {
        __syncthreads();
        #pragma unroll
        for (int i = 0; i < 32; ++i) {
            int e = i * 256 + t; int pxl = e >> 7; int ci = e & 127;
            hTn[((size_t)img * 576 + px0 + pxl) * 128 + ci] = f2bf(tile[ci][pxl]);
        }
    }
}

// ------------------------------------------------------------------- launcher
extern "C" void kernel_launch(void* const* d_in, const int* in_sizes, int n_in,
                              void* d_out, int out_size, void* d_ws, size_t ws_size,
                              hipStream_t stream)
{
    const float* x      = (const float*)d_in[0];
    const float* Wf_w   = (const float*)d_in[1];
    const float* Wf_b   = (const float*)d_in[2];
    const float* Wh_w   = (const float*)d_in[3];
    const float* Wh_b   = (const float*)d_in[4];
    const float* Wl_w   = (const float*)d_in[5];
    const float* Wl_b   = (const float*)d_in[6];
    const float* alpha  = (const float*)d_in[7];
    const float* Wc     = (const float*)d_in[8];
    const float* Wg_w   = (const float*)d_in[9];
    const float* Wg_b   = (const float*)d_in[10];
    const float* bng    = (const float*)d_in[11];
    const float* bnb    = (const float*)d_in[12];
    const float* zr_w   = (const float*)d_in[13];
    const float* zr_b   = (const float*)d_in[14];
    const float* gh_w   = (const float*)d_in[15];
    const float* gh_b   = (const float*)d_in[16];
    const float* intraw = (const float*)d_in[17];
    const float* interw = (const float*)d_in[18];
    float* outp = (float*)d_out;

    float* f = (float*)d_ws;
    const size_t SZ = (size_t)SB * C_ * N_;
    float* hbuf  = f; f += SZ;
    float* eii   = f; f += SZ;
    float* zrp   = f; f += 4 * (size_t)SB * C2 * N_;
    float* hhp   = f; f += 4 * SZ;
    float* wsumb = f; f += (size_t)NPAIR * C_ * 9;
    float* gbuf  = f; f += (size_t)NPAIR * C_;
    unsigned short* us = (unsigned short*)f;
    unsigned short* mji16  = us; us += (size_t)NPAIR * C_ * N_;
    unsigned short* hT16   = us; us += SZ;
    unsigned short* hc16   = us; us += SZ;           // VFi inter / rhbT16
    unsigned short* msgT16 = us; us += SZ;
    unsigned short* ftT    = us; us += SZ;           // Q intra / KFi inter
    unsigned short* KFa    = us; us += SZ;
    unsigned short* VFa    = us; us += SZ;
    unsigned short* Wp3    = us; us += (size_t)384 * 1152;
    unsigned short* Wpzr   = us; us += (size_t)256 * 6400;
    unsigned short* Wph    = us; us += (size_t)128 * 6400;
    unsigned short* Wcb    = us; us += (size_t)128 * 128;

    unsigned short* KFi    = ftT;
    unsigned short* VFi    = hc16;
    unsigned short* rhbT16 = hc16;

    packA3_kernel<<<(384 * 1152 + 255) / 256, 256, 0, stream>>>(Wf_w, Wh_w, Wl_w, Wp3);
    packA5_kernel<<<(256 * 6400 + 255) / 256, 256, 0, stream>>>(zr_w, Wpzr, 256);
    packA5_kernel<<<(128 * 6400 + 255) / 256, 256, 0, stream>>>(gh_w, Wph, 128);
    packWc_kernel<<<64, 256, 0, stream>>>(Wc, Wcb);

    // initial transpose/packs from x
    tc_kernel<<<dim3(9, SB), 256, 0, stream>>>(x, nullptr, nullptr, hT16, VFi);

    const float* hcur = x;
    for (int it = 0; it < 3; ++it) {
        float* hout = (it == 2) ? outp : hbuf;

        conv_mfma<3, 1, 128, 1, 1><<<dim3(6, 3, SB), 256, 0, stream>>>(
            hT16, hT16, Wp3, 384, nullptr, Wf_b, Wh_b, Wl_b, ftT, KFa, VFa);
        attn_mfma<0><<<dim3(36, SB), 256, 0, stream>>>(ftT, KFa, VFa, eii, nullptr, hcur, alpha);
        yt_mfma<<<dim3(36, SB), 256, 0, stream>>>(hT16, Wcb, KFi);
        attn_mfma<1><<<dim3(36, NPAIR), 256, 0, stream>>>(hT16, KFi, VFi, nullptr, mji16, nullptr, nullptr);
        wsum_kernel<<<dim3(NPAIR, C_), 64, 0, stream>>>(mji16, wsumb);
        g_kernel<<<NPAIR, 128, 0, stream>>>(wsumb, Wg_w, Wg_b, gbuf);
        msg_tc_kernel<<<dim3(9, SB), 256, 0, stream>>>(eii, mji16, gbuf, bng, bnb, intraw, interw, msgT16);
        conv_mfma<5, 2, 256, 4, 0><<<dim3(16, 3, SB), 256, 0, stream>>>(
            msgT16, hT16, Wpzr, 256, zrp, nullptr, nullptr, nullptr, nullptr, nullptr, nullptr);
        tc_kernel<<<dim3(9, SB), 256, 0, stream>>>(hcur, zrp, zr_b, rhbT16, nullptr);
        conv_mfma<5, 2, 256, 4, 0><<<dim3(8, 3, SB), 256, 0, stream>>>(
            msgT16, rhbT16, Wph, 128, hhp, nullptr, nullptr, nullptr, nullptr, nullptr, nullptr);
        update_tc_kernel<<<dim3(9, SB), 256, 0, stream>>>(
            zrp, zr_b, hhp, gh_b, hcur, hout, hT16, VFi, (it == 2) ? 1 : 0);
        hcur = hout;
    }
}

// Round 13
// 615.440 us; speedup vs baseline: 1.5599x; 1.4443x over previous
//
#include <hip/hip_runtime.h>
#include <math.h>

#define S_  5
#define B_  2
#define C_  128
#define N_  576
#define SB  10
#define NPAIR 40
#define C2  256

typedef short v8s __attribute__((ext_vector_type(8)));
typedef float v4f __attribute__((ext_vector_type(4)));

#define GLOBAL_AS __attribute__((address_space(1)))
#define LDS_AS    __attribute__((address_space(3)))

__device__ __forceinline__ unsigned short f2bf(float f) {
    union { float f; unsigned u; } v; v.f = f;
    unsigned r = (v.u + 0x7FFF + ((v.u >> 16) & 1)) >> 16;
    return (unsigned short)r;
}
__device__ __forceinline__ float bf2f(unsigned short h) {
    union { unsigned u; float f; } v; v.u = ((unsigned)h) << 16;
    return v.f;
}

// ------------------------------------------------------------------ weight packs
// Fragment-major A: [cgb][kk][ch][g][tap_l][c(4)][l15(16)][quad(4)][j(8)]
__global__ void packA5_kernel(const float* __restrict__ w, unsigned short* __restrict__ Apk, int M)
{
    int idx = blockIdx.x * 256 + threadIdx.x;
    if (idx >= M * 6400) return;
    int r = idx;
    int j = r & 7;      r >>= 3;
    int quad = r & 3;   r >>= 2;
    int l15 = r & 15;   r >>= 4;
    int c = r & 3;      r >>= 2;
    int tap_l = r % 5;  r /= 5;
    int g = r % 5;      r /= 5;
    int ch = r & 1;     r >>= 1;
    int kk = r & 3;     r >>= 2;
    int cgb = r;
    int co = cgb * 64 + c * 16 + l15;
    int ci = kk * 64 + ch * 32 + quad * 8 + j;
    int tap = g * 5 + tap_l;
    Apk[idx] = f2bf(w[((size_t)co * 256 + ci) * 25 + tap]);
}
__global__ void packA3_kernel(const float* __restrict__ wf, const float* __restrict__ wh,
                              const float* __restrict__ wl, unsigned short* __restrict__ Apk)
{
    int idx = blockIdx.x * 256 + threadIdx.x;
    if (idx >= 384 * 1152) return;
    int r = idx;
    int j = r & 7;      r >>= 3;
    int quad = r & 3;   r >>= 2;
    int l15 = r & 15;   r >>= 4;
    int c = r & 3;      r >>= 2;
    int tap_l = r % 3;  r /= 3;
    int g = r % 3;      r /= 3;
    int ch = r & 1;     r >>= 1;
    int kk = r & 1;     r >>= 1;
    int cgb = r;
    int co = cgb * 64 + c * 16 + l15;
    const float* w = (co < 128) ? wf : (co < 256) ? wh : wl;
    int cl = co & 127;
    int ci = kk * 64 + ch * 32 + quad * 8 + j;
    int tap = g * 3 + tap_l;
    Apk[idx] = f2bf(w[((size_t)cl * 128 + ci) * 9 + tap]);
}
__global__ void packWc_kernel(const float* __restrict__ w, unsigned short* __restrict__ o)
{
    int idx = blockIdx.x * 256 + threadIdx.x;
    if (idx < 128 * 128) o[idx] = f2bf(w[idx]);
}
// Wg[co][i] -> WgT[i][co]  (coalesced g_kernel reads)
__global__ void packWgT_kernel(const float* __restrict__ w, float* __restrict__ o)
{
    int idx = blockIdx.x * 256 + threadIdx.x;
    if (idx >= 128 * 1152) return;
    int co = idx & 127, i = idx >> 7;
    o[(size_t)i * 128 + co] = w[(size_t)co * 1152 + i];
}

// ---------------------------------------------- transpose-cast (x at it=0, rhb)
// 8-px tiles, grid (72, SB): high block count for latency-bound elementwise work
__global__ __launch_bounds__(256) void tc_kernel(
    const float* __restrict__ src, const float* __restrict__ zrp,
    const float* __restrict__ zrb,
    unsigned short* __restrict__ dst, unsigned short* __restrict__ vfd)
{
    const size_t PLANE = (size_t)SB * C2 * N_;
    __shared__ float tile[128][9];
    int img = blockIdx.y, px0 = blockIdx.x * 8, t = threadIdx.x;
    #pragma unroll
    for (int i = 0; i < 4; ++i) {
        int e = i * 256 + t; int ci = e >> 3; int px = e & 7;
        float v = src[((size_t)img * 128 + ci) * 576 + px0 + px];
        if (zrp) {
            size_t zi = ((size_t)img * C2 + 128 + ci) * 576 + px0 + px;
            float a = zrb[128 + ci];
            #pragma unroll
            for (int k = 0; k < 4; ++k) a += zrp[k * PLANE + zi];
            v *= 1.f / (1.f + __expf(-a));
        }
        tile[ci][px] = v;
        if (vfd) {
            int m = px0 + px;
            int ctile = ci >> 4, l15v = ci & 15;
            int sIdx = m >> 5, quadv = (m >> 3) & 3, j = m & 7;
            vfd[(((size_t)img * 8 + ctile) * 18 + sIdx) * 512 + (quadv * 16 + l15v) * 8 + j] = f2bf(v);
        }
    }
    __syncthreads();
    #pragma unroll
    for (int i = 0; i < 4; ++i) {
        int e = i * 256 + t; int pxl = e >> 7; int ci = e & 127;
        dst[((size_t)img * 576 + px0 + pxl) * 128 + ci] = f2bf(tile[ci][pxl]);
    }
}

// ------------------------------------------------------ MFMA implicit-GEMM conv v7
// MODE 0: f32 partial planes per kk (5x5 convs, SPLITK=4)
// MODE 1: conv3 full-K fused epilogue: +bias, write ftT(Q) / KFa(K-pack) / VFa(V-pack)
template<int KD, int R, int CINT, int SPLITK, int MODE>
__global__ __launch_bounds__(256, 1) void conv_mfma(
    const unsigned short* __restrict__ srcA, const unsigned short* __restrict__ srcB,
    const unsigned short* __restrict__ Apk, int COUT, float* __restrict__ po,
    const float* __restrict__ b0, const float* __restrict__ b1, const float* __restrict__ b2,
    unsigned short* __restrict__ t0, unsigned short* __restrict__ t1,
    unsigned short* __restrict__ t2)
{
    constexpr int PART   = CINT / SPLITK;
    constexpr int NCH    = PART / 32;
    constexpr int NSUB   = NCH * KD;
    constexpr int WR     = 8 + 2 * R;
    constexpr int WC     = 24 + 2 * R;
    constexpr int NPOS   = WR * WC;
    constexpr int NSLOTB = NPOS * 4;
    constexpr int RB     = (NSLOTB + 255) / 256;
    constexpr int AUNITS = KD * 4 * 64;
    constexpr int AR     = AUNITS / 256;
    __shared__ __align__(16) unsigned short Ab[2][AUNITS * 8];
    __shared__ __align__(16) unsigned short Bb[NPOS * 32];

    int f   = blockIdx.x;
    int kk  = f % SPLITK;
    int cgb = f / SPLITK;
    int pxb = blockIdx.y;
    int img = blockIdx.z;
    int t = threadIdx.x;
    int wave = t >> 6, lane = t & 63;
    int quad = lane >> 4, l15 = lane & 15;
    int r0 = pxb * 8;

    const int cibase = kk * PART;
    const unsigned short* src = (cibase >= 128) ? srcB : srcA;
    const int cioff0 = cibase & 127;
    const unsigned short* srcI = src + (size_t)img * 576 * 128;

    int posBase[3], pxs[3];
    #pragma unroll
    for (int s = 0; s < 3; ++s) {
        int px = pxb * 192 + wave * 48 + s * 16 + l15;
        pxs[s] = px;
        int pr = px / 24, pc = px % 24;
        posBase[s] = (pr - r0 + R) * WC + pc + R;
    }

    int goffB[RB]; bool gokB[RB];
    #pragma unroll
    for (int rr = 0; rr < RB; ++rr) {
        int idx = rr * 256 + wave * 64 + lane;
        int pos = idx >> 2, slotq = idx & 3;
        int gr = slotq ^ ((pos >> 1) & 3);
        int wr = pos / WC, wc = pos % WC;
        int grow = r0 - R + wr, gcol = wc - R;
        gokB[rr] = (idx < NSLOTB) && grow >= 0 && grow < 24 && gcol >= 0 && gcol < 24;
        goffB[rr] = (grow * 24 + gcol) * 128 + gr * 8;
    }

    auto stageB = [&](int ch) {
        const unsigned short* sp = srcI + cioff0 + ch * 32;
        #pragma unroll
        for (int rr = 0; rr < RB; ++rr) {
            if (gokB[rr]) {
                __builtin_amdgcn_global_load_lds(
                    (const GLOBAL_AS void*)(sp + goffB[rr]),
                    (LDS_AS void*)((char*)&Bb[0] + (size_t)(rr * 256 + wave * 64) * 16),
                    16, 0, 0);
            }
        }
    };
    auto stageA = [&](int sub, int buf) {
        const unsigned short* sp = Apk + ((size_t)((cgb * SPLITK + kk) * NSUB + sub)) * (AUNITS * 8);
        #pragma unroll
        for (int r = 0; r < AR; ++r) {
            int u0 = r * 256 + wave * 64;
            __builtin_amdgcn_global_load_lds(
                (const GLOBAL_AS void*)(sp + (size_t)(u0 + lane) * 8),
                (LDS_AS void*)((char*)&Ab[buf][0] + (size_t)u0 * 16),
                16, 0, 0);
        }
    };

    v4f acc[4][3];
    #pragma unroll
    for (int c = 0; c < 4; ++c)
        #pragma unroll
        for (int s = 0; s < 3; ++s)
            #pragma unroll
            for (int r = 0; r < 4; ++r) acc[c][s][r] = 0.f;

    {
        v8s zv;
        #pragma unroll
        for (int j = 0; j < 8; ++j) zv[j] = 0;
        for (int i = t; i < NPOS * 4; i += 256) ((v8s*)Bb)[i] = zv;
    }
    __syncthreads();
    stageB(0);
    stageA(0, 0);
    __syncthreads();

    int sub = 0;
    #pragma unroll 1
    for (int ch = 0; ch < NCH; ++ch) {
        #pragma unroll 1
        for (int g = 0; g < KD; ++g) {
            if (sub + 1 < NSUB) stageA(sub + 1, (sub + 1) & 1);
            const unsigned short* Ap = &Ab[sub & 1][0];
            #pragma unroll
            for (int tl = 0; tl < KD; ++tl) {
                int doff = (g - R) * WC + (tl - R);
                v8s a[4];
                #pragma unroll
                for (int c = 0; c < 4; ++c)
                    a[c] = *(const v8s*)&Ap[((tl * 4 + c) * 64 + l15 * 4 + quad) * 8];
                v8s b[3];
                #pragma unroll
                for (int s = 0; s < 3; ++s) {
                    int pos = posBase[s] + doff;
                    b[s] = *(const v8s*)&Bb[pos * 32 + ((quad ^ ((pos >> 1) & 3)) << 3)];
                }
                #pragma unroll
                for (int c = 0; c < 4; ++c)
                    #pragma unroll
                    for (int s = 0; s < 3; ++s)
                        acc[c][s] = __builtin_amdgcn_mfma_f32_16x16x32_bf16(a[c], b[s], acc[c][s], 0, 0, 0);
            }
            __syncthreads();
            ++sub;
        }
        if (ch + 1 < NCH) { stageB(ch + 1); __syncthreads(); }
    }

    if (MODE == 0) {
        float* out = po + (size_t)kk * ((size_t)SB * COUT * 576)
                   + ((size_t)img * COUT + cgb * 64) * 576;
        #pragma unroll
        for (int c = 0; c < 4; ++c)
            #pragma unroll
            for (int s = 0; s < 3; ++s)
                #pragma unroll
                for (int r = 0; r < 4; ++r) {
                    int col = c * 16 + quad * 4 + r;
                    out[(size_t)col * 576 + pxs[s]] = acc[c][s][r];
                }
    } else {
        #pragma unroll
        for (int c = 0; c < 4; ++c)
            #pragma unroll
            for (int s = 0; s < 3; ++s) {
                int px = pxs[s];
                #pragma unroll
                for (int r = 0; r < 4; ++r) {
                    int co = cgb * 64 + c * 16 + quad * 4 + r;
                    int which = co >> 7, cl = co & 127;
                    const float* bp = (which == 0) ? b0 : (which == 1) ? b1 : b2;
                    float v = acc[c][s][r] + bp[cl];
                    if (which == 0) {
                        t0[((size_t)img * 576 + px) * 128 + cl] = f2bf(v);
                    } else if (which == 1) {
                        int mt = px >> 4, l15m = px & 15;
                        int kb = cl >> 5, quadk = (cl >> 3) & 3, jj = cl & 7;
                        t1[(((size_t)img * 36 + mt) * 4 + kb) * 512 + (quadk * 16 + l15m) * 8 + jj] = f2bf(v);
                    } else {
                        int ctile = cl >> 4, l15v = cl & 15;
                        int sIdx = px >> 5, quadv = (px >> 3) & 3, jj = px & 7;
                        t2[(((size_t)img * 8 + ctile) * 18 + sIdx) * 512 + (quadv * 16 + l15v) * 8 + jj] = f2bf(v);
                    }
                }
            }
    }
}

// ---------------------------------------------------------------- yt (MFMA) -> K-packed
__global__ __launch_bounds__(256) void yt_mfma(
    const unsigned short* __restrict__ hT, const unsigned short* __restrict__ Wcb,
    unsigned short* __restrict__ KFi)
{
    int t = threadIdx.x, wave = t >> 6, lane = t & 63;
    int q = lane >> 4, l15 = lane & 15;
    int n0 = blockIdx.x * 16, img = blockIdx.y;
    v4f acc[2];
    #pragma unroll
    for (int ct = 0; ct < 2; ++ct)
        #pragma unroll
        for (int r = 0; r < 4; ++r) acc[ct][r] = 0.f;
    #pragma unroll
    for (int kk = 0; kk < 4; ++kk) {
        v8s b = *(const v8s*)(hT + ((size_t)img * 576 + n0 + l15) * 128 + kk * 32 + q * 8);
        #pragma unroll
        for (int ct = 0; ct < 2; ++ct) {
            v8s a = *(const v8s*)(Wcb + (size_t)((wave * 2 + ct) * 16 + l15) * 128 + kk * 32 + q * 8);
            acc[ct] = __builtin_amdgcn_mfma_f32_16x16x32_bf16(a, b, acc[ct], 0, 0, 0);
        }
    }
    int mt = blockIdx.x;
    #pragma unroll
    for (int ct = 0; ct < 2; ++ct) {
        #pragma unroll
        for (int r = 0; r < 4; ++r) {
            int co = (wave * 2 + ct) * 16 + q * 4 + r;
            int kk = co >> 5, quadk = (co >> 3) & 3, j = co & 7;
            KFi[(((size_t)img * 36 + mt) * 4 + kk) * 512 + (quadk * 16 + l15) * 8 + j]
                = f2bf(acc[ct][r]);
        }
    }
}

// ---------------------------------------------------- MFMA flash attention
template<int MODE>
__global__ __launch_bounds__(256) void attn_mfma(
    const unsigned short* __restrict__ QT, const unsigned short* __restrict__ KF,
    const unsigned short* __restrict__ VF, float* __restrict__ Of,
    unsigned short* __restrict__ Oh, const float* __restrict__ addsrc,
    const float* __restrict__ alpha)
{
    __shared__ __align__(16) unsigned short P[16 * 576];
    __shared__ float redmx[4][16];
    __shared__ float redsm[4][16];
    int t = threadIdx.x;
    int wave = t >> 6, lane = t & 63;
    int q = lane >> 4, l15 = lane & 15;
    int n0 = blockIdx.x * 16;
    int p = blockIdx.y;
    int qimg, kimg;
    if (MODE == 0) { qimg = p; kimg = p; }
    else {
        int b = p & 1; int ij = p >> 1; int i = ij >> 2; int jj = ij & 3;
        int j = jj + (jj >= i ? 1 : 0);
        qimg = i * 2 + b; kimg = j * 2 + b;
    }
    const unsigned short* Qp = QT + ((size_t)qimg * 576 + n0) * 128;
    const unsigned short* Kp = KF + (size_t)kimg * 36 * 4 * 512;
    const unsigned short* Vp = VF + (size_t)kimg * 8 * 18 * 512;

    v8s aq[4];
    #pragma unroll
    for (int kk = 0; kk < 4; ++kk)
        aq[kk] = *(const v8s*)(Qp + (size_t)l15 * 128 + kk * 32 + q * 8);

    v4f S[9];
    #pragma unroll
    for (int i = 0; i < 9; ++i)
        #pragma unroll
        for (int r = 0; r < 4; ++r) S[i][r] = 0.f;

    #pragma unroll
    for (int i = 0; i < 9; ++i) {
        int mt = wave * 9 + i;
        #pragma unroll
        for (int kk = 0; kk < 4; ++kk) {
            v8s b = *(const v8s*)(Kp + ((size_t)(mt * 4 + kk)) * 512 + lane * 8);
            S[i] = __builtin_amdgcn_mfma_f32_16x16x32_bf16(aq[kk], b, S[i], 0, 0, 0);
        }
    }

    float mx[4];
    #pragma unroll
    for (int r = 0; r < 4; ++r) {
        float m = S[0][r];
        #pragma unroll
        for (int i = 1; i < 9; ++i) m = fmaxf(m, S[i][r]);
        #pragma unroll
        for (int off = 1; off < 16; off <<= 1) m = fmaxf(m, __shfl_xor(m, off));
        mx[r] = m;
    }
    if (l15 == 0) {
        #pragma unroll
        for (int r = 0; r < 4; ++r) redmx[wave][q * 4 + r] = mx[r];
    }
    __syncthreads();
    float sum[4];
    #pragma unroll
    for (int r = 0; r < 4; ++r) {
        float g = fmaxf(fmaxf(redmx[0][q * 4 + r], redmx[1][q * 4 + r]),
                        fmaxf(redmx[2][q * 4 + r], redmx[3][q * 4 + r]));
        float s = 0.f;
        #pragma unroll
        for (int i = 0; i < 9; ++i) { float e = __expf(S[i][r] - g); S[i][r] = e; s += e; }
        #pragma unroll
        for (int off = 1; off < 16; off <<= 1) s += __shfl_xor(s, off);
        sum[r] = s;
    }
    if (l15 == 0) {
        #pragma unroll
        for (int r = 0; r < 4; ++r) redsm[wave][q * 4 + r] = sum[r];
    }
    #pragma unroll
    for (int i = 0; i < 9; ++i) {
        int m = (wave * 9 + i) * 16 + l15;
        int cm = m >> 3, mo = m & 7;
        #pragma unroll
        for (int r = 0; r < 4; ++r) {
            int n = q * 4 + r;
            P[n * 576 + ((cm ^ (n & 7)) << 3) + mo] = f2bf(S[i][r]);
        }
    }
    __syncthreads();
    float inv[4];
    #pragma unroll
    for (int r = 0; r < 4; ++r)
        inv[r] = 1.f / (redsm[0][q * 4 + r] + redsm[1][q * 4 + r] +
                        redsm[2][q * 4 + r] + redsm[3][q * 4 + r]);

    v4f o[2];
    #pragma unroll
    for (int ct = 0; ct < 2; ++ct)
        #pragma unroll
        for (int r = 0; r < 4; ++r) o[ct][r] = 0.f;

    for (int s = 0; s < 18; ++s) {
        int cm = s * 4 + q;
        v8s a = *(const v8s*)&P[l15 * 576 + ((cm ^ (l15 & 7)) << 3)];
        #pragma unroll
        for (int ct = 0; ct < 2; ++ct) {
            int ctile = wave * 2 + ct;
            v8s b = *(const v8s*)(Vp + ((size_t)(ctile * 18 + s)) * 512 + lane * 8);
            o[ct] = __builtin_amdgcn_mfma_f32_16x16x32_bf16(a, b, o[ct], 0, 0, 0);
        }
    }

    #pragma unroll
    for (int ct = 0; ct < 2; ++ct) {
        int c = (wave * 2 + ct) * 16 + l15;
        size_t base = ((size_t)p * 128 + c) * 576 + n0 + q * 4;
        if (MODE == 0) {
            float al = alpha[0];
            #pragma unroll
            for (int r = 0; r < 4; ++r)
                Of[base + r] = al * o[ct][r] * inv[r] + addsrc[base + r];
        } else {
            #pragma unroll
            for (int r = 0; r < 4; ++r)
                Oh[base + r] = f2bf(o[ct][r] * inv[r]);
        }
    }
}

// ------------------------------------- window sums for analytic gate-conv mean
__global__ __launch_bounds__(64) void wsum_kernel(
    const unsigned short* __restrict__ mji, float* __restrict__ wsum)
{
    int pair = blockIdx.x, ci = blockIdx.y, lane = threadIdx.x;
    const unsigned short* p = mji + ((size_t)pair * C_ + ci) * N_;
    float T=0, R0=0, R23=0, Cl=0, Cr=0, c00=0, c0w=0, ch0=0, chw=0;
    for (int i = lane; i < N_; i += 64) {
        float v = bf2f(p[i]);
        int r = i / 24, cc = i % 24;
        T += v;
        if (r == 0)  R0  += v;
        if (r == 23) R23 += v;
        if (cc == 0)  Cl += v;
        if (cc == 23) Cr += v;
        if (i == 0)   c00 = v;
        if (i == 23)  c0w = v;
        if (i == 552) ch0 = v;
        if (i == 575) chw = v;
    }
    #pragma unroll
    for (int off = 32; off > 0; off >>= 1) {
        T  += __shfl_xor(T, off);  R0 += __shfl_xor(R0, off);  R23 += __shfl_xor(R23, off);
        Cl += __shfl_xor(Cl, off); Cr += __shfl_xor(Cr, off);
        c00 += __shfl_xor(c00, off); c0w += __shfl_xor(c0w, off);
        ch0 += __shfl_xor(ch0, off); chw += __shfl_xor(chw, off);
    }
    if (lane == 0) {
        float rowsub[3] = {R23, 0.f, R0};
        float colsub[3] = {Cr,  0.f, Cl};
        float corner[9] = {chw, 0.f, ch0,  0.f, 0.f, 0.f,  c0w, 0.f, c00};
        float* o = wsum + ((size_t)pair * C_ + ci) * 9;
        #pragma unroll
        for (int ky = 0; ky < 3; ++ky)
            #pragma unroll
            for (int kx = 0; kx < 3; ++kx)
                o[ky * 3 + kx] = T - rowsub[ky] - colsub[kx] + corner[ky * 3 + kx];
    }
}

// gate: coalesced via WgT
__global__ __launch_bounds__(128) void g_kernel(
    const float* __restrict__ wsum, const float* __restrict__ WgT,
    const float* __restrict__ Wgb, float* __restrict__ g)
{
    __shared__ float sw[C_ * 9];
    int pair = blockIdx.x; int co = threadIdx.x;
    for (int i = co; i < C_ * 9; i += 128) sw[i] = wsum[(size_t)pair * C_ * 9 + i];
    __syncthreads();
    float acc = 0.f;
    for (int i = 0; i < C_ * 9; ++i) acc += WgT[(size_t)i * 128 + co] * sw[i];
    float m = acc * (1.f / 576.f) + Wgb[co];
    g[pair * C_ + co] = 1.f / (1.f + __expf(-m));
}

// ----------------------- fused msg compute + transpose-cast -> msgT16 [px][c]
__global__ __launch_bounds__(256) void msg_tc_kernel(
    const float* __restrict__ eii, const unsigned short* __restrict__ mji,
    const float* __restrict__ g, const float* __restrict__ bn_gamma,
    const float* __restrict__ bn_beta, const float* __restrict__ intra_w,
    const float* __restrict__ inter_w, unsigned short* __restrict__ msgT)
{
    __shared__ float tile[128][9];
    int img = blockIdx.y, px0 = blockIdx.x * 8, t = threadIdx.x;
    int s = img >> 1, b = img & 1;
    float iw = intra_w[0], ew = inter_w[0];
    #pragma unroll
    for (int i = 0; i < 4; ++i) {
        int e = i * 256 + t; int ci = e >> 3; int pxl = e & 7;
        int px = px0 + pxl;
        float scale = bn_gamma[ci] * rsqrtf(1.f + 1e-5f);
        float acc = 0.f;
        #pragma unroll
        for (int jj = 0; jj < 4; ++jj) {
            int pidx = (s * 4 + jj) * 2 + b;
            acc += g[pidx * C_ + ci] * bf2f(mji[((size_t)pidx * C_ + ci) * N_ + px]);
        }
        float inter = scale * acc + 4.f * bn_beta[ci];
        tile[ci][pxl] = iw * eii[((size_t)img * C_ + ci) * N_ + px] + ew * inter;
    }
    __syncthreads();
    #pragma unroll
    for (int i = 0; i < 4; ++i) {
        int e = i * 256 + t; int pxl = e >> 7; int ci = e & 127;
        msgT[((size_t)img * 576 + px0 + pxl) * 128 + ci] = f2bf(tile[ci][pxl]);
    }
}

// -------- fused GRU update + next-iter transpose/packs (hT [px][c], VF pack)
__global__ __launch_bounds__(256) void update_tc_kernel(
    const float* __restrict__ zrp, const float* __restrict__ zrb,
    const float* __restrict__ hhp, const float* __restrict__ ghb,
    const float* __restrict__ h, float* __restrict__ out,
    unsigned short* __restrict__ hTn, unsigned short* __restrict__ VFn, int last)
{
    const size_t ZP = (size_t)SB * C2 * N_;
    const size_t HP = (size_t)SB * C_ * N_;
    __shared__ float tile[128][9];
    int img = blockIdx.y, px0 = blockIdx.x * 8, t = threadIdx.x;
    #pragma unroll
    for (int i = 0; i < 4; ++i) {
        int e = i * 256 + t; int ci = e >> 3; int pxl = e & 7;
        int px = px0 + pxl;
        size_t zi = ((size_t)img * C2 + ci) * N_ + px;
        float za = zrb[ci];
        #pragma unroll
        for (int k = 0; k < 4; ++k) za += zrp[k * ZP + zi];
        float z = 1.f / (1.f + __expf(-za));
        size_t hi = ((size_t)img * C_ + ci) * N_ + px;
        float ha = ghb[ci];
        #pragma unroll
        for (int k = 0; k < 4; ++k) ha += hhp[k * HP + hi];
        float hh = tanhf(ha);
        float o = (2.f - z) * h[hi] + z * hh;
        out[hi] = o;
        tile[ci][pxl] = o;
        if (!last) {
            int ctile = ci >> 4, l15v = ci & 15;
            int sIdx = px >> 5, quadv = (px >> 3) & 3, j = px & 7;
            VFn[(((size_t)img * 8 + ctile) * 18 + sIdx) * 512 + (quadv * 16 + l15v) * 8 + j] = f2bf(o);
        }
    }
    if (!last) {
        __syncthreads();
        #pragma unroll
        for (int i = 0; i < 4; ++i) {
            int e = i * 256 + t; int pxl = e >> 7; int ci = e & 127;
            hTn[((size_t)img * 576 + px0 + pxl) * 128 + ci] = f2bf(tile[ci][pxl]);
        }
    }
}

// ------------------------------------------------------------------- launcher
extern "C" void kernel_launch(void* const* d_in, const int* in_sizes, int n_in,
                              void* d_out, int out_size, void* d_ws, size_t ws_size,
                              hipStream_t stream)
{
    const float* x      = (const float*)d_in[0];
    const float* Wf_w   = (const float*)d_in[1];
    const float* Wf_b   = (const float*)d_in[2];
    const float* Wh_w   = (const float*)d_in[3];
    const float* Wh_b   = (const float*)d_in[4];
    const float* Wl_w   = (const float*)d_in[5];
    const float* Wl_b   = (const float*)d_in[6];
    const float* alpha  = (const float*)d_in[7];
    const float* Wc     = (const float*)d_in[8];
    const float* Wg_w   = (const float*)d_in[9];
    const float* Wg_b   = (const float*)d_in[10];
    const float* bng    = (const float*)d_in[11];
    const float* bnb    = (const float*)d_in[12];
    const float* zr_w   = (const float*)d_in[13];
    const float* zr_b   = (const float*)d_in[14];
    const float* gh_w   = (const float*)d_in[15];
    const float* gh_b   = (const float*)d_in[16];
    const float* intraw = (const float*)d_in[17];
    const float* interw = (const float*)d_in[18];
    float* outp = (float*)d_out;

    float* f = (float*)d_ws;
    const size_t SZ = (size_t)SB * C_ * N_;
    float* hbuf  = f; f += SZ;
    float* eii   = f; f += SZ;
    float* zrp   = f; f += 4 * (size_t)SB * C2 * N_;
    float* hhp   = f; f += 4 * SZ;
    float* wsumb = f; f += (size_t)NPAIR * C_ * 9;
    float* gbuf  = f; f += (size_t)NPAIR * C_;
    float* WgT   = f; f += (size_t)128 * 1152;
    unsigned short* us = (unsigned short*)f;
    unsigned short* mji16  = us; us += (size_t)NPAIR * C_ * N_;
    unsigned short* hT16   = us; us += SZ;
    unsigned short* hc16   = us; us += SZ;           // VFi inter / rhbT16
    unsigned short* msgT16 = us; us += SZ;
    unsigned short* ftT    = us; us += SZ;           // Q intra / KFi inter
    unsigned short* KFa    = us; us += SZ;
    unsigned short* VFa    = us; us += SZ;
    unsigned short* Wp3    = us; us += (size_t)384 * 1152;
    unsigned short* Wpzr   = us; us += (size_t)256 * 6400;
    unsigned short* Wph    = us; us += (size_t)128 * 6400;
    unsigned short* Wcb    = us; us += (size_t)128 * 128;

    unsigned short* KFi    = ftT;
    unsigned short* VFi    = hc16;
    unsigned short* rhbT16 = hc16;

    packA3_kernel<<<(384 * 1152 + 255) / 256, 256, 0, stream>>>(Wf_w, Wh_w, Wl_w, Wp3);
    packA5_kernel<<<(256 * 6400 + 255) / 256, 256, 0, stream>>>(zr_w, Wpzr, 256);
    packA5_kernel<<<(128 * 6400 + 255) / 256, 256, 0, stream>>>(gh_w, Wph, 128);
    packWc_kernel<<<64, 256, 0, stream>>>(Wc, Wcb);
    packWgT_kernel<<<(128 * 1152 + 255) / 256, 256, 0, stream>>>(Wg_w, WgT);

    // initial transpose/packs from x
    tc_kernel<<<dim3(72, SB), 256, 0, stream>>>(x, nullptr, nullptr, hT16, VFi);

    const float* hcur = x;
    for (int it = 0; it < 3; ++it) {
        float* hout = (it == 2) ? outp : hbuf;

        conv_mfma<3, 1, 128, 1, 1><<<dim3(6, 3, SB), 256, 0, stream>>>(
            hT16, hT16, Wp3, 384, nullptr, Wf_b, Wh_b, Wl_b, ftT, KFa, VFa);
        attn_mfma<0><<<dim3(36, SB), 256, 0, stream>>>(ftT, KFa, VFa, eii, nullptr, hcur, alpha);
        yt_mfma<<<dim3(36, SB), 256, 0, stream>>>(hT16, Wcb, KFi);
        attn_mfma<1><<<dim3(36, NPAIR), 256, 0, stream>>>(hT16, KFi, VFi, nullptr, mji16, nullptr, nullptr);
        wsum_kernel<<<dim3(NPAIR, C_), 64, 0, stream>>>(mji16, wsumb);
        g_kernel<<<NPAIR, 128, 0, stream>>>(wsumb, WgT, Wg_b, gbuf);
        msg_tc_kernel<<<dim3(72, SB), 256, 0, stream>>>(eii, mji16, gbuf, bng, bnb, intraw, interw, msgT16);
        conv_mfma<5, 2, 256, 4, 0><<<dim3(16, 3, SB), 256, 0, stream>>>(
            msgT16, hT16, Wpzr, 256, zrp, nullptr, nullptr, nullptr, nullptr, nullptr, nullptr);
        tc_kernel<<<dim3(72, SB), 256, 0, stream>>>(hcur, zrp, zr_b, rhbT16, nullptr);
        conv_mfma<5, 2, 256, 4, 0><<<dim3(8, 3, SB), 256, 0, stream>>>(
            msgT16, rhbT16, Wph, 128, hhp, nullptr, nullptr, nullptr, nullptr, nullptr, nullptr);
        update_tc_kernel<<<dim3(72, SB), 256, 0, stream>>>(
            zrp, zr_b, hhp, gh_b, hcur, hout, hT16, VFi, (it == 2) ? 1 : 0);
        hcur = hout;
    }
}